// Round 1
// baseline (876.125 us; speedup 1.0000x reference)
//
#include <hip/hip_runtime.h>
#include <math.h>

// Problem constants (fixed by the reference)
#define HID   768
#define DIMD  192
#define NSIG  15
#define BB    32
#define SS    4096
#define INV_SCALE 0.07216878364870322f   // 1/sqrt(192)
#define LOG_S     8.31776616671934f      // ln(4096)
#define NCHUNK 16
#define SC     256                        // tokens per ctx block

// Workspace layout in floats (~31.5 MB total)
#define WS_QK    ((size_t)0)
#define WS_QB    (WS_QK + NSIG*HID)                 // 11520
#define WS_ATTN  (WS_QB + 64)                       // 11584
#define WS_M     (WS_ATTN + (size_t)BB*NSIG*SS)     // +1966080
#define WS_INVL  (WS_M + BB*NSIG)
#define WS_CTXP  (WS_INVL + BB*NSIG)                // + 512*15*768

// ---------------- Kernel A: Qk[n][h] = (q[n,:]·Wk[h,:])/sqrt(d), qb[n] = (q[n]·bk)/sqrt(d)
__global__ __launch_bounds__(256) void k_qk(const float* __restrict__ q,
                                            const float* __restrict__ Wk,
                                            const float* __restrict__ bk,
                                            float* __restrict__ ws) {
  int idx = blockIdx.x * 256 + threadIdx.x;
  if (idx < NSIG * HID) {
    int n = idx / HID, h = idx - n * HID;
    const float* qr = q + n * DIMD;
    const float* wr = Wk + h * DIMD;
    float s = 0.f;
    #pragma unroll 4
    for (int d = 0; d < DIMD; ++d) s = fmaf(qr[d], wr[d], s);
    ws[WS_QK + (size_t)n * HID + h] = s * INV_SCALE;
  }
  if (idx < NSIG) {
    const float* qr = q + idx * DIMD;
    float s = 0.f;
    for (int d = 0; d < DIMD; ++d) s = fmaf(qr[d], bk[d], s);
    ws[WS_QB + idx] = s * INV_SCALE;
  }
}

// ---------------- Kernel B: attn[b][n][s] = X[b,s,:]·Qk[n,:] + qb[n]
// thread-per-token, 256 tokens/block; X chunk staged in LDS (pad-1 f4 row = 17 floats),
// full Qk resident in LDS (broadcast reads). Static LDS = 63488 B -> 2 blocks/CU.
#define HC 16
__global__ __launch_bounds__(256) void k_logits(const float* __restrict__ X,
                                                const float* __restrict__ ws_qk,
                                                const float* __restrict__ ws_qb,
                                                float* __restrict__ attn) {
  __shared__ float Qs[NSIG * HID];       // 46080 B
  __shared__ float Xs[256 * (HC + 1)];   // 17408 B
  const int t  = threadIdx.x;
  const int s0 = blockIdx.x * 256;
  const int b  = blockIdx.y;

  #pragma unroll
  for (int k = 0; k < (NSIG * HID) / 256; ++k)   // 45 coalesced copies
    Qs[t + k * 256] = ws_qk[t + k * 256];

  float acc[NSIG];
  #pragma unroll
  for (int n = 0; n < NSIG; ++n) acc[n] = ws_qb[n];

  const float* Xb = X + ((size_t)(b * SS + s0)) * HID;

  for (int c = 0; c < HID / HC; ++c) {           // 48 h-chunks
    __syncthreads();
    // stage X[256][HC] -> LDS, coalesced float4 global loads
    #pragma unroll
    for (int k = 0; k < 4; ++k) {
      int j  = t + k * 256;                      // float4 index, 1024 total
      int r  = j >> 2, cc = j & 3;
      float4 xv = *(const float4*)(Xb + (size_t)r * HID + c * HC + cc * 4);
      float* dst = Xs + r * (HC + 1) + cc * 4;
      dst[0] = xv.x; dst[1] = xv.y; dst[2] = xv.z; dst[3] = xv.w;
    }
    __syncthreads();
    const float* xrow = Xs + t * (HC + 1);
    #pragma unroll
    for (int c4 = 0; c4 < HC / 4; ++c4) {
      float x0 = xrow[c4*4+0], x1 = xrow[c4*4+1], x2 = xrow[c4*4+2], x3 = xrow[c4*4+3];
      #pragma unroll
      for (int n = 0; n < NSIG; ++n) {
        float4 qv = *(const float4*)(Qs + n * HID + c * HC + c4 * 4);  // broadcast b128
        acc[n] = fmaf(x0, qv.x, acc[n]);
        acc[n] = fmaf(x1, qv.y, acc[n]);
        acc[n] = fmaf(x2, qv.z, acc[n]);
        acc[n] = fmaf(x3, qv.w, acc[n]);
      }
    }
  }
  #pragma unroll
  for (int n = 0; n < NSIG; ++n)                  // coalesced stores
    attn[((size_t)(b * NSIG + n)) * SS + s0 + t] = acc[n];
}

// ---------------- Kernel C: per (b,n): m, l, sum(e*a) -> entropy, strength; store m, 1/l
__global__ __launch_bounds__(256) void k_softmax_stats(const float* __restrict__ attn,
                                                       float* __restrict__ m_out,
                                                       float* __restrict__ invl_out,
                                                       float* __restrict__ out) {
  const int blk = blockIdx.x;                      // 0..479
  const int b = blk / NSIG, n = blk - b * NSIG;
  const float* row = attn + ((size_t)(b * NSIG + n)) * SS;
  const int t = threadIdx.x;
  __shared__ float red[8];

  float m = -1e30f;
  for (int i = t; i < SS; i += 256) m = fmaxf(m, row[i]);
  #pragma unroll
  for (int o = 32; o > 0; o >>= 1) m = fmaxf(m, __shfl_down(m, o, 64));
  if ((t & 63) == 0) red[t >> 6] = m;
  __syncthreads();
  m = fmaxf(fmaxf(red[0], red[1]), fmaxf(red[2], red[3]));

  float l = 0.f, pa = 0.f;
  for (int i = t; i < SS; i += 256) {
    float a = row[i];
    float e = expf(a - m);
    l += e; pa = fmaf(e, a, pa);
  }
  #pragma unroll
  for (int o = 32; o > 0; o >>= 1) { l += __shfl_down(l, o, 64); pa += __shfl_down(pa, o, 64); }
  __syncthreads();
  if ((t & 63) == 0) { red[t >> 6] = l; red[4 + (t >> 6)] = pa; }
  __syncthreads();
  if (t == 0) {
    float L  = red[0] + red[1] + red[2] + red[3];
    float PA = red[4] + red[5] + red[6] + red[7];
    float entropy = m + logf(L) - PA / L;          // = -sum w*log w
    m_out[blk]    = m;
    invl_out[blk] = 1.f / L;
    out[b * (2 * NSIG) + NSIG + n] = 1.f - entropy / LOG_S;
  }
}

// ---------------- Kernel D: ctx partials. Block = (b, 256-token chunk).
// Thread owns h = {t, t+256, t+512} x 15 signals in registers (45 acc).
__global__ __launch_bounds__(256) void k_ctx(const float* __restrict__ X,
                                             const float* __restrict__ attn,
                                             const float* __restrict__ m_arr,
                                             const float* __restrict__ invl_arr,
                                             float* __restrict__ ctxp) {
  __shared__ float wLDS[NSIG * SC];                // 15360 B
  const int t = threadIdx.x;
  const int chunk = blockIdx.x, b = blockIdx.y;
  const int s0 = chunk * SC;

  #pragma unroll
  for (int n = 0; n < NSIG; ++n) {
    float a = attn[((size_t)(b * NSIG + n)) * SS + s0 + t];
    wLDS[n * SC + t] = expf(a - m_arr[b * NSIG + n]) * invl_arr[b * NSIG + n];
  }
  __syncthreads();

  float acc[NSIG * 3];
  #pragma unroll
  for (int i = 0; i < NSIG * 3; ++i) acc[i] = 0.f;

  const float* Xb = X + ((size_t)(b * SS + s0)) * HID + t;
  for (int s = 0; s < SC; s += 4) {
    float x[12];
    #pragma unroll
    for (int j = 0; j < 4; ++j)
      #pragma unroll
      for (int k = 0; k < 3; ++k)
        x[j * 3 + k] = Xb[(size_t)(s + j) * HID + k * 256];   // coalesced b32
    #pragma unroll
    for (int n = 0; n < NSIG; ++n) {
      float4 wv = *(const float4*)(wLDS + n * SC + s);        // broadcast b128
      float wa[4] = {wv.x, wv.y, wv.z, wv.w};
      #pragma unroll
      for (int j = 0; j < 4; ++j)
        #pragma unroll
        for (int k = 0; k < 3; ++k)
          acc[n * 3 + k] = fmaf(wa[j], x[j * 3 + k], acc[n * 3 + k]);
    }
  }
  float* dst = ctxp + ((size_t)((b * NCHUNK + chunk) * NSIG)) * HID;
  #pragma unroll
  for (int n = 0; n < NSIG; ++n)
    #pragma unroll
    for (int k = 0; k < 3; ++k)
      dst[(size_t)n * HID + k * 256 + t] = acc[n * 3 + k];    // coalesced
}

// ---------------- Kernel E: per (b,n): reduce ctx, se = ctx·Wv + bv, MLP(gelu), effect
__global__ __launch_bounds__(256) void k_final(const float* __restrict__ ctxp,
                                               const float* __restrict__ Wv,
                                               const float* __restrict__ bv,
                                               const float* __restrict__ nullemb,
                                               const float* __restrict__ W1,
                                               const float* __restrict__ b1,
                                               const float* __restrict__ W2,
                                               const float* __restrict__ b2,
                                               float* __restrict__ out) {
  const int blk = blockIdx.x;                      // 0..479
  const int b = blk / NSIG, n = blk - b * NSIG;
  const int t = threadIdx.x;
  __shared__ float ctx[HID];
  __shared__ float se[DIMD];

  #pragma unroll
  for (int k = 0; k < 3; ++k) {
    int h = t + k * 256;
    float s = 0.f;
    #pragma unroll 4
    for (int c = 0; c < NCHUNK; ++c)
      s += ctxp[((size_t)((b * NCHUNK + c) * NSIG + n)) * HID + h];
    ctx[h] = s;
  }
  __syncthreads();
  if (t < DIMD) {
    float s = bv[t];
    #pragma unroll 4
    for (int h = 0; h < HID; ++h)
      s = fmaf(ctx[h], Wv[(size_t)h * DIMD + t], s);
    se[t] = s;
  }
  __syncthreads();
  if (t < 64) {
    float s = b1[t];
    const float* nrow = nullemb + (size_t)n * HID;
    #pragma unroll 4
    for (int i = 0; i < DIMD; ++i) s = fmaf(se[i],   W1[(size_t)i * 64 + t], s);
    #pragma unroll 4
    for (int i = 0; i < DIMD; ++i) s = fmaf(nrow[i], W1[(size_t)(DIMD + i) * 64 + t], s);
    float g = 0.5f * s * (1.f + erff(s * 0.70710678118654752f));  // exact gelu
    float val = g * W2[t];
    #pragma unroll
    for (int o = 32; o > 0; o >>= 1) val += __shfl_down(val, o, 64);
    if (t == 0) out[b * (2 * NSIG) + n] = val + b2[0];
  }
}

extern "C" void kernel_launch(void* const* d_in, const int* in_sizes, int n_in,
                              void* d_out, int out_size, void* d_ws, size_t ws_size,
                              hipStream_t stream) {
  const float* X   = (const float*)d_in[0];
  const float* Wk  = (const float*)d_in[1];
  const float* bk  = (const float*)d_in[2];
  const float* Wv  = (const float*)d_in[3];
  const float* bv  = (const float*)d_in[4];
  const float* q   = (const float*)d_in[5];
  const float* nul = (const float*)d_in[6];
  const float* W1  = (const float*)d_in[7];
  const float* b1  = (const float*)d_in[8];
  const float* W2  = (const float*)d_in[9];
  const float* b2  = (const float*)d_in[10];
  float* out = (float*)d_out;
  float* ws  = (float*)d_ws;    // needs ~31.5 MB

  hipLaunchKernelGGL(k_qk, dim3(45), dim3(256), 0, stream, q, Wk, bk, ws);
  hipLaunchKernelGGL(k_logits, dim3(SS / 256, BB), dim3(256), 0, stream,
                     X, ws + WS_QK, ws + WS_QB, ws + WS_ATTN);
  hipLaunchKernelGGL(k_softmax_stats, dim3(BB * NSIG), dim3(256), 0, stream,
                     ws + WS_ATTN, ws + WS_M, ws + WS_INVL, out);
  hipLaunchKernelGGL(k_ctx, dim3(NCHUNK, BB), dim3(256), 0, stream,
                     X, ws + WS_ATTN, ws + WS_M, ws + WS_INVL, ws + WS_CTXP);
  hipLaunchKernelGGL(k_final, dim3(BB * NSIG), dim3(256), 0, stream,
                     ws + WS_CTXP, Wv, bv, nul, W1, b1, W2, b2, out);
}